// Round 4
// baseline (496.663 us; speedup 1.0000x reference)
//
#include <hip/hip_runtime.h>
#include <math.h>

#define BB 8
#define NN 8192
#define DD 128
#define MM 256
#define DVV 128
#define PP 32        // split-N partial blocks per batch (per feature half)
#define CHUNK 32     // tokens per chunk

#define XSCALE 0.29730177875068026f
#define INV_SQRT_M 0.0625f

typedef _Float16 f16x8 __attribute__((ext_vector_type(8)));
typedef float f32x16 __attribute__((ext_vector_type(16)));

// LDS fragment slab: 64 lanes x 8 halves, stride 520 (16B-aligned, bank-spread)
#define FR(s, l) ((s) * 520 + (l) * 8)

__device__ __forceinline__ unsigned f2ord(float f) {
    unsigned u = __float_as_uint(f);
    return (u & 0x80000000u) ? ~u : (u | 0x80000000u);
}
__device__ __forceinline__ float ord2f(unsigned u) {
    return (u & 0x80000000u) ? __uint_as_float(u & 0x7fffffffu) : __uint_as_float(~u);
}
__device__ __forceinline__ f32x16 mfma16(f16x8 a, f16x8 b, f32x16 c) {
    return __builtin_amdgcn_mfma_f32_32x32x16_f16(a, b, c, 0, 0, 0);
}
__device__ __forceinline__ int rowf(int r, int q) { return (r & 3) + 8 * (r >> 2) + 4 * q; }

// Stage X (A-operand): src row-major [32][128] fp32 -> scaled hi/lo f16 frags in R1.
__device__ __forceinline__ void stage_A(const float* __restrict__ src,
                                        _Float16* R1, float* hs, float* msk,
                                        const float* __restrict__ mrow, bool do_h) {
    const int tid = threadIdx.x;
    const int t = tid >> 3, ks = tid & 7;
    const float4* s4 = (const float4*)(src + t * DD + ks * 16);
    float x[16];
    #pragma unroll
    for (int u = 0; u < 4; ++u) {
        float4 v = s4[u];
        x[u*4+0] = v.x * XSCALE; x[u*4+1] = v.y * XSCALE;
        x[u*4+2] = v.z * XSCALE; x[u*4+3] = v.w * XSCALE;
    }
    if (do_h) {
        float p = 0.f;
        #pragma unroll
        for (int u = 0; u < 16; ++u) p += x[u] * x[u];
        p += __shfl_xor(p, 1, 64); p += __shfl_xor(p, 2, 64); p += __shfl_xor(p, 4, 64);
        if (ks == 0) { hs[t] = 0.5f * p; msk[t] = mrow[t]; }
    }
    #pragma unroll
    for (int q = 0; q < 2; ++q) {
        f16x8 h8, l8;
        #pragma unroll
        for (int j = 0; j < 8; ++j) {
            float xv = x[q*8 + j];
            _Float16 h = (_Float16)xv;
            h8[j] = h; l8[j] = (_Float16)(xv - (float)h);
        }
        *(f16x8*)&R1[FR(0*8 + ks, q*32 + t)] = h8;
        *(f16x8*)&R1[FR(1*8 + ks, q*32 + t)] = l8;
    }
}

// Stage V (B-operand): src [32 rows=k][128 cols=n] fp32 -> hi/lo frags in R1.
__device__ __forceinline__ void stage_BV(const float* __restrict__ src, _Float16* R1) {
    const int tid = threadIdx.x;
    const int t = tid >> 3, c0 = (tid & 7) * 16;
    const int ts = t >> 4, qq = (t >> 3) & 1, j = t & 7;
    const float4* s4 = (const float4*)(src + t * DVV + c0);
    #pragma unroll
    for (int u = 0; u < 4; ++u) {
        float4 v = s4[u];
        float vv[4] = {v.x, v.y, v.z, v.w};
        #pragma unroll
        for (int e = 0; e < 4; ++e) {
            int c = c0 + u*4 + e;
            int vt = c >> 5, iv = c & 31;
            _Float16 h = (_Float16)vv[e];
            R1[FR((0*4 + vt)*2 + ts, qq*32 + iv) + j] = h;
            R1[FR((1*4 + vt)*2 + ts, qq*32 + iv) + j] = (_Float16)(vv[e] - (float)h);
        }
    }
}

// ---------------------------------------------------------------------------
// pack: omega -> B-frag layout hi/lo f16 in ws; init kmaxord
// ---------------------------------------------------------------------------
__global__ __launch_bounds__(256) void pack_kernel(const float* __restrict__ omega,
                                                   _Float16* __restrict__ omh,
                                                   _Float16* __restrict__ oml,
                                                   unsigned* __restrict__ kmaxord) {
    int g = blockIdx.x * 256 + threadIdx.x;    // 0..4095
    if (g < BB) kmaxord[g] = f2ord(-INFINITY);
    int lane = g & 63, ks = (g >> 6) & 7, nt = g >> 9;
    int q = lane >> 5, i = lane & 31;
    f16x8 h8, l8;
    #pragma unroll
    for (int j = 0; j < 8; ++j) {
        float w = omega[(size_t)(ks*16 + q*8 + j) * MM + nt*32 + i];
        _Float16 h = (_Float16)w;
        h8[j] = h; l8[j] = (_Float16)(w - (float)h);
    }
    ((f16x8*)omh)[g] = h8;
    ((f16x8*)oml)[g] = l8;
}

// ---------------------------------------------------------------------------
// kmax: per-batch max of U_K (hi*hi only -- mx error cancels in the ratio)
// grid (32 tokblk, 2 fhalf, BB)
// ---------------------------------------------------------------------------
__global__ __launch_bounds__(256, 4) void kmax_kernel(const float* __restrict__ K,
                                                      const _Float16* __restrict__ omh,
                                                      unsigned* __restrict__ kmaxord) {
    __shared__ __align__(16) _Float16 R1[16 * 520];
    __shared__ float wred[4];
    const int b = blockIdx.z;
    const int tid = threadIdx.x, w = tid >> 6, lane = tid & 63;
    const int nt = blockIdx.y * 4 + w;

    f16x8 om[8];
    #pragma unroll
    for (int k = 0; k < 8; ++k)
        om[k] = ((const f16x8*)omh)[(nt*8 + k)*64 + lane];

    float mx = -INFINITY;
    for (int c = 0; c < 8; ++c) {
        int t0 = (blockIdx.x * 8 + c) * CHUNK;
        __syncthreads();
        stage_A(K + ((size_t)b*NN + t0) * DD, R1, nullptr, nullptr, nullptr, false);
        __syncthreads();
        f32x16 a0;
        #pragma unroll
        for (int r = 0; r < 16; ++r) a0[r] = 0.f;
        #pragma unroll
        for (int ks = 0; ks < 8; ++ks) {
            f16x8 ah = *(const f16x8*)&R1[FR(ks, lane)];
            a0 = mfma16(ah, om[ks], a0);
        }
        #pragma unroll
        for (int r = 0; r < 16; ++r) mx = fmaxf(mx, a0[r]);
    }
    #pragma unroll
    for (int off = 1; off < 64; off <<= 1) mx = fmaxf(mx, __shfl_xor(mx, off, 64));
    if (lane == 0) wred[w] = mx;
    __syncthreads();
    if (tid == 0)
        atomicMax(kmaxord + b,
                  f2ord(fmaxf(fmaxf(wred[0], wred[1]), fmaxf(wred[2], wred[3]))));
}

// ---------------------------------------------------------------------------
// kv: U_K (3-mfma split) -> Kp -> LDS transpose -> KV = Kp^T V (3-mfma split)
// grid (PP, 2 fhalf, BB); wave handles ONE feature tile nt = fh*4+w.
// omega frags streamed from global (L2-hot) each chunk.
// ---------------------------------------------------------------------------
__global__ __launch_bounds__(256, 3) void kv_kernel(const float* __restrict__ K,
                                                    const float* __restrict__ V,
                                                    const float* __restrict__ mask,
                                                    const _Float16* __restrict__ omh,
                                                    const _Float16* __restrict__ oml,
                                                    const unsigned* __restrict__ kmaxord,
                                                    float* __restrict__ pkv,
                                                    float* __restrict__ pks) {
    __shared__ __align__(16) _Float16 R1[16 * 520];  // A-frags, then V-frags
    __shared__ __align__(16) _Float16 R2[16 * 520];  // Kp frags
    __shared__ float hs[32], msk[32];
    const int b = blockIdx.z, p = blockIdx.x;
    const int tid = threadIdx.x, w = tid >> 6, lane = tid & 63;
    const int i = tid & 31, q = (tid >> 5) & 1;
    const int nt = blockIdx.y * 4 + w;
    const float kmaxv = ord2f(kmaxord[b]);
    const f16x8* om4h = (const f16x8*)omh;
    const f16x8* om4l = (const f16x8*)oml;

    f32x16 kvacc[4];
    #pragma unroll
    for (int vt = 0; vt < 4; ++vt)
        #pragma unroll
        for (int r = 0; r < 16; ++r) kvacc[vt][r] = 0.f;
    float ksa = 0.f;

    for (int c = 0; c < 8; ++c) {
        int t0 = (p * 8 + c) * CHUNK;
        __syncthreads();
        stage_A(K + ((size_t)b*NN + t0) * DD, R1, hs, msk,
                mask + (size_t)b*NN + t0, true);
        __syncthreads();

        f32x16 a0;
        #pragma unroll
        for (int r = 0; r < 16; ++r) a0[r] = 0.f;
        #pragma unroll
        for (int ks = 0; ks < 8; ++ks) {
            f16x8 oh = om4h[(nt*8 + ks)*64 + lane];
            f16x8 ol = om4l[(nt*8 + ks)*64 + lane];
            f16x8 ah = *(const f16x8*)&R1[FR(ks, lane)];
            f16x8 al = *(const f16x8*)&R1[FR(8 + ks, lane)];
            a0 = mfma16(ah, oh, a0);
            a0 = mfma16(ah, ol, a0);
            a0 = mfma16(al, oh, a0);
        }
        __syncthreads();   // R1 A-reads done -> restage as V; write Kp to R2

        stage_BV(V + ((size_t)b*NN + t0) * DVV, R1);
        #pragma unroll
        for (int r = 0; r < 16; ++r) {
            int tok = rowf(r, q);
            float hh = hs[tok] + kmaxv;
            float mm = msk[tok] * INV_SQRT_M;
            int ts = tok >> 4, qq = (tok >> 3) & 1, j = tok & 7;
            float kp = (__expf(a0[r] - hh) + 1e-4f) * mm;
            ksa += kp;
            _Float16 h = (_Float16)kp;
            R2[FR(w*4 + ts, qq*32 + i) + j] = h;
            R2[FR(w*4 + 2 + ts, qq*32 + i) + j] = (_Float16)(kp - (float)h);
        }
        __syncthreads();

        f16x8 ah[2], al[2];
        #pragma unroll
        for (int ts = 0; ts < 2; ++ts) {
            ah[ts] = *(const f16x8*)&R2[FR(w*4 + ts, lane)];
            al[ts] = *(const f16x8*)&R2[FR(w*4 + 2 + ts, lane)];
        }
        #pragma unroll
        for (int vt = 0; vt < 4; ++vt) {
            #pragma unroll
            for (int ts = 0; ts < 2; ++ts) {
                f16x8 bh = *(const f16x8*)&R1[FR(vt*2 + ts, lane)];
                f16x8 bl = *(const f16x8*)&R1[FR(8 + vt*2 + ts, lane)];
                kvacc[vt] = mfma16(ah[ts], bh, kvacc[vt]);
                kvacc[vt] = mfma16(ah[ts], bl, kvacc[vt]);
                kvacc[vt] = mfma16(al[ts], bh, kvacc[vt]);
            }
        }
    }

    float* dst = pkv + ((size_t)(b * PP + p) << 15);
    #pragma unroll
    for (int vt = 0; vt < 4; ++vt)
        #pragma unroll
        for (int r = 0; r < 16; ++r) {
            int feat = nt*32 + rowf(r, q);
            dst[feat * DVV + vt*32 + i] = kvacc[vt][r];
        }
    {
        float s = ksa + __shfl_xor(ksa, 32, 64);
        if (q == 0) pks[(size_t)(b * PP + p) * MM + nt*32 + i] = s;
    }
}

// ---------------------------------------------------------------------------
// reduce: sum P partials -> ksum fp32 + KV as hi/lo f16 B-frags (global)
// ---------------------------------------------------------------------------
__global__ __launch_bounds__(256) void reduce_kernel(const float* __restrict__ pkv,
                                                     const float* __restrict__ pks,
                                                     float* __restrict__ ksum,
                                                     _Float16* __restrict__ kvph,
                                                     _Float16* __restrict__ kvpl) {
    const int b = blockIdx.y;
    int g = blockIdx.x * 256 + threadIdx.x;     // 0..32767
    float s = 0.f;
    for (int p = 0; p < PP; ++p) s += pkv[((size_t)(b * PP + p) << 15) + g];
    int f = g >> 7, v = g & 127;
    int vt = v >> 5, iv = v & 31, fs = f >> 4, qq = (f >> 3) & 1, j = f & 7;
    size_t idx = (size_t)b * 32768 + (size_t)((vt*16 + fs)*64 + qq*32 + iv)*8 + j;
    _Float16 h = (_Float16)s;
    kvph[idx] = h;
    kvpl[idx] = (_Float16)(s - (float)h);
    if (blockIdx.x == 0) {
        float ss = 0.f;
        for (int p = 0; p < PP; ++p) ss += pks[(size_t)(b * PP + p) * MM + g];
        ksum[b * MM + g] = ss;
    }
}

// ---------------------------------------------------------------------------
// out: U_Q -> per-token max -> Qp frags -> Out = Qp@KV (MFMA), norm via MFMA
// grid (128 tokblk, BB), 2 chunks each; omega/KV frags streamed from global.
// ---------------------------------------------------------------------------
__global__ __launch_bounds__(256, 3) void out_kernel(const float* __restrict__ Q,
                                                     const float* __restrict__ mask,
                                                     const _Float16* __restrict__ omh,
                                                     const _Float16* __restrict__ oml,
                                                     const float* __restrict__ ksum,
                                                     const _Float16* __restrict__ kvph,
                                                     const _Float16* __restrict__ kvpl,
                                                     float* __restrict__ out) {
    __shared__ __align__(16) _Float16 R1[16 * 520];
    __shared__ __align__(16) _Float16 R2[32 * 520];
    __shared__ float hs[32], msk[32], wmax[4][32], norms[32];
    const int b = blockIdx.y;
    const int tid = threadIdx.x, w = tid >> 6, lane = tid & 63;
    const int i = tid & 31, q = (tid >> 5) & 1;
    const f16x8* om4h = (const f16x8*)omh;
    const f16x8* om4l = (const f16x8*)oml;
    const f16x8* kvh4 = (const f16x8*)kvph;
    const f16x8* kvl4 = (const f16x8*)kvpl;

    f16x8 bnh[4], bnl[4];     // Ksum column frags, fsteps w*4..w*4+3
    #pragma unroll
    for (int u = 0; u < 4; ++u) {
        f16x8 hh, ll;
        #pragma unroll
        for (int j = 0; j < 8; ++j) { hh[j] = (_Float16)0.f; ll[j] = (_Float16)0.f; }
        if (i == 0) {
            #pragma unroll
            for (int j = 0; j < 8; ++j) {
                float s = ksum[b * MM + (4*w + u)*16 + q*8 + j];
                _Float16 h = (_Float16)s;
                hh[j] = h; ll[j] = (_Float16)(s - (float)h);
            }
        }
        bnh[u] = hh; bnl[u] = ll;
    }

    for (int c = 0; c < 2; ++c) {
        int t0 = (blockIdx.x * 2 + c) * CHUNK;
        __syncthreads();
        stage_A(Q + ((size_t)b*NN + t0) * DD, R1, hs, msk,
                mask + (size_t)b*NN + t0, true);
        if (tid < 32) norms[tid] = 1e-8f;
        __syncthreads();

        f32x16 a0, a1;
        #pragma unroll
        for (int r = 0; r < 16; ++r) { a0[r] = 0.f; a1[r] = 0.f; }
        #pragma unroll
        for (int ks = 0; ks < 8; ++ks) {
            f16x8 o0h = om4h[((2*w + 0)*8 + ks)*64 + lane];
            f16x8 o0l = om4l[((2*w + 0)*8 + ks)*64 + lane];
            f16x8 o1h = om4h[((2*w + 1)*8 + ks)*64 + lane];
            f16x8 o1l = om4l[((2*w + 1)*8 + ks)*64 + lane];
            f16x8 ah = *(const f16x8*)&R1[FR(ks, lane)];
            f16x8 al = *(const f16x8*)&R1[FR(8 + ks, lane)];
            a0 = mfma16(ah, o0h, a0);
            a0 = mfma16(ah, o0l, a0);
            a0 = mfma16(al, o0h, a0);
            a1 = mfma16(ah, o1h, a1);
            a1 = mfma16(ah, o1l, a1);
            a1 = mfma16(al, o1h, a1);
        }
        float tm[16];
        #pragma unroll
        for (int r = 0; r < 16; ++r) tm[r] = fmaxf(a0[r], a1[r]);
        #pragma unroll
        for (int off = 1; off < 32; off <<= 1)
            #pragma unroll
            for (int r = 0; r < 16; ++r) tm[r] = fmaxf(tm[r], __shfl_xor(tm[r], off, 64));
        if (i == 0)
            #pragma unroll
            for (int r = 0; r < 16; ++r) wmax[w][rowf(r, q)] = tm[r];
        __syncthreads();

        #pragma unroll
        for (int r = 0; r < 16; ++r) {
            int tok = rowf(r, q);
            float tmax = fmaxf(fmaxf(wmax[0][tok], wmax[1][tok]),
                               fmaxf(wmax[2][tok], wmax[3][tok]));
            float hh = hs[tok] + tmax;
            float mm = msk[tok] * INV_SQRT_M;
            #pragma unroll
            for (int n = 0; n < 2; ++n) {
                float qp = (__expf((n ? a1[r] : a0[r]) - hh) + 1e-4f) * mm;
                int feat = (2*w + n)*32 + i;
                int fstep = feat >> 4, fq = (i >> 3) & 1, fj = i & 7;
                _Float16 h = (_Float16)qp;
                R2[FR(fstep, fq*32 + tok) + fj] = h;
                R2[FR(16 + fstep, fq*32 + tok) + fj] = (_Float16)(qp - (float)h);
            }
        }
        __syncthreads();

        f32x16 oa, na;
        #pragma unroll
        for (int r = 0; r < 16; ++r) { oa[r] = 0.f; na[r] = 0.f; }
        #pragma unroll
        for (int fs = 0; fs < 16; ++fs) {
            f16x8 bh = kvh4[(size_t)b * 4096 + (w*16 + fs)*64 + lane];
            f16x8 bl = kvl4[(size_t)b * 4096 + (w*16 + fs)*64 + lane];
            f16x8 ah = *(const f16x8*)&R2[FR(fs, lane)];
            f16x8 al = *(const f16x8*)&R2[FR(16 + fs, lane)];
            oa = mfma16(ah, bh, oa);
            oa = mfma16(ah, bl, oa);
            oa = mfma16(al, bh, oa);
        }
        #pragma unroll
        for (int u = 0; u < 4; ++u) {
            f16x8 ah = *(const f16x8*)&R2[FR(4*w + u, lane)];
            f16x8 al = *(const f16x8*)&R2[FR(16 + 4*w + u, lane)];
            na = mfma16(ah, bnh[u], na);
            na = mfma16(ah, bnl[u], na);
            na = mfma16(al, bnh[u], na);
        }
        if (i == 0)
            #pragma unroll
            for (int r = 0; r < 16; ++r) atomicAdd(&norms[rowf(r, q)], na[r]);
        __syncthreads();

        float* ob = out + ((size_t)b*NN + t0) * DVV + w*32 + i;
        #pragma unroll
        for (int r = 0; r < 16; ++r) {
            int tok = rowf(r, q);
            ob[(size_t)tok * DVV] = oa[r] / norms[tok];
        }
    }
}

extern "C" void kernel_launch(void* const* d_in, const int* in_sizes, int n_in,
                              void* d_out, int out_size, void* d_ws, size_t ws_size,
                              hipStream_t stream) {
    const float* Q     = (const float*)d_in[0];
    const float* K     = (const float*)d_in[1];
    const float* V     = (const float*)d_in[2];
    const float* mask  = (const float*)d_in[3];
    const float* omega = (const float*)d_in[4];
    float* out = (float*)d_out;

    char* ws = (char*)d_ws;
    _Float16* omh    = (_Float16*)(ws);                       // 64 KB
    _Float16* oml    = (_Float16*)(ws + (64 << 10));          // 64 KB
    unsigned* kmaxord = (unsigned*)(ws + (128 << 10));        // 32 B
    float*    ksum   = (float*)(ws + (132 << 10));            // 8 KB
    float*    pks    = (float*)(ws + (140 << 10));            // 256 KB
    _Float16* kvph   = (_Float16*)(ws + (400 << 10));         // 512 KB
    _Float16* kvpl   = (_Float16*)(ws + (912 << 10));         // 512 KB
    float*    pkv    = (float*)(ws + (2 << 20));              // 32 MB

    pack_kernel<<<16, 256, 0, stream>>>(omega, omh, oml, kmaxord);
    kmax_kernel<<<dim3(32, 2, BB), 256, 0, stream>>>(K, omh, kmaxord);
    kv_kernel<<<dim3(PP, 2, BB), 256, 0, stream>>>(K, V, mask, omh, oml, kmaxord, pkv, pks);
    reduce_kernel<<<dim3(128, BB), 256, 0, stream>>>(pkv, pks, ksum, kvph, kvpl);
    out_kernel<<<dim3(128, BB), 256, 0, stream>>>(Q, mask, omh, oml, ksum, kvph, kvpl, out);
}

// Round 5
// 250.741 us; speedup vs baseline: 1.9808x; 1.9808x over previous
//
#include <hip/hip_runtime.h>
#include <math.h>

#define BB 8
#define NN 8192
#define DD 128
#define MM 256
#define DVV 128
#define PP 32        // split-N partial blocks per batch (per feature half)
#define CHUNK 32     // tokens per chunk

#define XSCALE 0.29730177875068026f
#define INV_SQRT_M 0.0625f

typedef _Float16 f16x8 __attribute__((ext_vector_type(8)));
typedef float f32x16 __attribute__((ext_vector_type(16)));

// LDS fragment slab: 64 lanes x 8 halves, stride 520 (16B-aligned, bank-spread)
#define FR(s, l) ((s) * 520 + (l) * 8)

__device__ __forceinline__ unsigned f2ord(float f) {
    unsigned u = __float_as_uint(f);
    return (u & 0x80000000u) ? ~u : (u | 0x80000000u);
}
__device__ __forceinline__ float ord2f(unsigned u) {
    return (u & 0x80000000u) ? __uint_as_float(u & 0x7fffffffu) : __uint_as_float(~u);
}
__device__ __forceinline__ f32x16 mfma16(f16x8 a, f16x8 b, f32x16 c) {
    return __builtin_amdgcn_mfma_f32_32x32x16_f16(a, b, c, 0, 0, 0);
}
__device__ __forceinline__ int rowf(int r, int q) { return (r & 3) + 8 * (r >> 2) + 4 * q; }

// Stage X (A-operand): src row-major [32][128] fp32 -> scaled hi/lo f16 frags in R1.
__device__ __forceinline__ void stage_A(const float* __restrict__ src,
                                        _Float16* R1, float* hs, float* msk,
                                        const float* __restrict__ mrow, bool do_h) {
    const int tid = threadIdx.x;
    const int t = tid >> 3, ks = tid & 7;
    const float4* s4 = (const float4*)(src + t * DD + ks * 16);
    float x[16];
    #pragma unroll
    for (int u = 0; u < 4; ++u) {
        float4 v = s4[u];
        x[u*4+0] = v.x * XSCALE; x[u*4+1] = v.y * XSCALE;
        x[u*4+2] = v.z * XSCALE; x[u*4+3] = v.w * XSCALE;
    }
    if (do_h) {
        float p = 0.f;
        #pragma unroll
        for (int u = 0; u < 16; ++u) p += x[u] * x[u];
        p += __shfl_xor(p, 1, 64); p += __shfl_xor(p, 2, 64); p += __shfl_xor(p, 4, 64);
        if (ks == 0) { hs[t] = 0.5f * p; msk[t] = mrow[t]; }
    }
    #pragma unroll
    for (int q = 0; q < 2; ++q) {
        f16x8 h8, l8;
        #pragma unroll
        for (int j = 0; j < 8; ++j) {
            float xv = x[q*8 + j];
            _Float16 h = (_Float16)xv;
            h8[j] = h; l8[j] = (_Float16)(xv - (float)h);
        }
        *(f16x8*)&R1[FR(0*8 + ks, q*32 + t)] = h8;
        *(f16x8*)&R1[FR(1*8 + ks, q*32 + t)] = l8;
    }
}

// Stage V (B-operand): src [32 rows=k][128 cols=n] fp32 -> hi/lo frags in R1.
__device__ __forceinline__ void stage_BV(const float* __restrict__ src, _Float16* R1) {
    const int tid = threadIdx.x;
    const int t = tid >> 3, c0 = (tid & 7) * 16;
    const int ts = t >> 4, qq = (t >> 3) & 1, j = t & 7;
    const float4* s4 = (const float4*)(src + t * DVV + c0);
    #pragma unroll
    for (int u = 0; u < 4; ++u) {
        float4 v = s4[u];
        float vv[4] = {v.x, v.y, v.z, v.w};
        #pragma unroll
        for (int e = 0; e < 4; ++e) {
            int c = c0 + u*4 + e;
            int vt = c >> 5, iv = c & 31;
            _Float16 h = (_Float16)vv[e];
            R1[FR((0*4 + vt)*2 + ts, qq*32 + iv) + j] = h;
            R1[FR((1*4 + vt)*2 + ts, qq*32 + iv) + j] = (_Float16)(vv[e] - (float)h);
        }
    }
}

// ---------------------------------------------------------------------------
// pack: omega -> B-frag layout hi/lo f16 in ws; init kmaxord
// ---------------------------------------------------------------------------
__global__ __launch_bounds__(256) void pack_kernel(const float* __restrict__ omega,
                                                   _Float16* __restrict__ omh,
                                                   _Float16* __restrict__ oml,
                                                   unsigned* __restrict__ kmaxord) {
    int g = blockIdx.x * 256 + threadIdx.x;    // 0..4095
    if (g < BB) kmaxord[g] = f2ord(-INFINITY);
    int lane = g & 63, ks = (g >> 6) & 7, nt = g >> 9;
    int q = lane >> 5, i = lane & 31;
    f16x8 h8, l8;
    #pragma unroll
    for (int j = 0; j < 8; ++j) {
        float w = omega[(size_t)(ks*16 + q*8 + j) * MM + nt*32 + i];
        _Float16 h = (_Float16)w;
        h8[j] = h; l8[j] = (_Float16)(w - (float)h);
    }
    ((f16x8*)omh)[g] = h8;
    ((f16x8*)oml)[g] = l8;
}

// ---------------------------------------------------------------------------
// kmax: per-batch max of U_K (hi*hi only -- mx error cancels in the ratio)
// grid (32 tokblk, 2 fhalf, BB); omega held in registers (light kernel)
// ---------------------------------------------------------------------------
__global__ __launch_bounds__(256, 4) void kmax_kernel(const float* __restrict__ K,
                                                      const _Float16* __restrict__ omh,
                                                      unsigned* __restrict__ kmaxord) {
    __shared__ __align__(16) _Float16 R1[16 * 520];
    __shared__ float wred[4];
    const int b = blockIdx.z;
    const int tid = threadIdx.x, w = tid >> 6, lane = tid & 63;
    const int nt = blockIdx.y * 4 + w;

    f16x8 om[8];
    #pragma unroll
    for (int k = 0; k < 8; ++k)
        om[k] = ((const f16x8*)omh)[(nt*8 + k)*64 + lane];

    float mx = -INFINITY;
    for (int c = 0; c < 8; ++c) {
        int t0 = (blockIdx.x * 8 + c) * CHUNK;
        __syncthreads();
        stage_A(K + ((size_t)b*NN + t0) * DD, R1, nullptr, nullptr, nullptr, false);
        __syncthreads();
        f32x16 a0;
        #pragma unroll
        for (int r = 0; r < 16; ++r) a0[r] = 0.f;
        #pragma unroll
        for (int ks = 0; ks < 8; ++ks) {
            f16x8 ah = *(const f16x8*)&R1[FR(ks, lane)];
            a0 = mfma16(ah, om[ks], a0);
        }
        #pragma unroll
        for (int r = 0; r < 16; ++r) mx = fmaxf(mx, a0[r]);
    }
    #pragma unroll
    for (int off = 1; off < 64; off <<= 1) mx = fmaxf(mx, __shfl_xor(mx, off, 64));
    if (lane == 0) wred[w] = mx;
    __syncthreads();
    if (tid == 0)
        atomicMax(kmaxord + b,
                  f2ord(fmaxf(fmaxf(wred[0], wred[1]), fmaxf(wred[2], wred[3]))));
}

// ---------------------------------------------------------------------------
// kv: U_K (3-mfma split) -> Kp -> LDS transpose -> KV = Kp^T V (3-mfma split)
// grid (PP, 2 fhalf, BB); wave handles ONE feature tile nt = fh*4+w.
// omega frags held in REGISTERS (32 VGPRs), kvacc 64 VGPRs -> ~160 total.
// NO forced min-waves (R4 lesson: forcing 3 waves/EU spilled accumulators,
// FETCH/WRITE exploded 330/342 MB).
// ---------------------------------------------------------------------------
__global__ __launch_bounds__(256) void kv_kernel(const float* __restrict__ K,
                                                 const float* __restrict__ V,
                                                 const float* __restrict__ mask,
                                                 const _Float16* __restrict__ omh,
                                                 const _Float16* __restrict__ oml,
                                                 const unsigned* __restrict__ kmaxord,
                                                 float* __restrict__ pkv,
                                                 float* __restrict__ pks) {
    __shared__ __align__(16) _Float16 R1[16 * 520];  // A-frags, then V-frags
    __shared__ __align__(16) _Float16 R2[16 * 520];  // Kp frags
    __shared__ float hs[32], msk[32];
    const int b = blockIdx.z, p = blockIdx.x;
    const int tid = threadIdx.x, w = tid >> 6, lane = tid & 63;
    const int i = tid & 31, q = (tid >> 5) & 1;
    const int nt = blockIdx.y * 4 + w;
    const float kmaxv = ord2f(kmaxord[b]);

    f16x8 oh[8], ol[8];
    #pragma unroll
    for (int k = 0; k < 8; ++k) {
        oh[k] = ((const f16x8*)omh)[(nt*8 + k)*64 + lane];
        ol[k] = ((const f16x8*)oml)[(nt*8 + k)*64 + lane];
    }

    f32x16 kvacc[4];
    #pragma unroll
    for (int vt = 0; vt < 4; ++vt)
        #pragma unroll
        for (int r = 0; r < 16; ++r) kvacc[vt][r] = 0.f;
    float ksa = 0.f;

    for (int c = 0; c < 8; ++c) {
        int t0 = (p * 8 + c) * CHUNK;
        __syncthreads();
        stage_A(K + ((size_t)b*NN + t0) * DD, R1, hs, msk,
                mask + (size_t)b*NN + t0, true);
        __syncthreads();

        f32x16 a0;
        #pragma unroll
        for (int r = 0; r < 16; ++r) a0[r] = 0.f;
        #pragma unroll
        for (int ks = 0; ks < 8; ++ks) {
            f16x8 ah = *(const f16x8*)&R1[FR(ks, lane)];
            f16x8 al = *(const f16x8*)&R1[FR(8 + ks, lane)];
            a0 = mfma16(ah, oh[ks], a0);
            a0 = mfma16(ah, ol[ks], a0);
            a0 = mfma16(al, oh[ks], a0);
        }
        __syncthreads();   // R1 A-reads done -> restage as V; write Kp to R2

        stage_BV(V + ((size_t)b*NN + t0) * DVV, R1);
        #pragma unroll
        for (int r = 0; r < 16; ++r) {
            int tok = rowf(r, q);
            float hh = hs[tok] + kmaxv;
            float mm = msk[tok] * INV_SQRT_M;
            int ts = tok >> 4, qq = (tok >> 3) & 1, j = tok & 7;
            float kp = (__expf(a0[r] - hh) + 1e-4f) * mm;
            ksa += kp;
            _Float16 h = (_Float16)kp;
            R2[FR(w*4 + ts, qq*32 + i) + j] = h;
            R2[FR(w*4 + 2 + ts, qq*32 + i) + j] = (_Float16)(kp - (float)h);
        }
        __syncthreads();

        f16x8 ah[2], al[2];
        #pragma unroll
        for (int ts = 0; ts < 2; ++ts) {
            ah[ts] = *(const f16x8*)&R2[FR(w*4 + ts, lane)];
            al[ts] = *(const f16x8*)&R2[FR(w*4 + 2 + ts, lane)];
        }
        #pragma unroll
        for (int vt = 0; vt < 4; ++vt) {
            #pragma unroll
            for (int ts = 0; ts < 2; ++ts) {
                f16x8 bh = *(const f16x8*)&R1[FR(vt*2 + ts, lane)];
                f16x8 bl = *(const f16x8*)&R1[FR(8 + vt*2 + ts, lane)];
                kvacc[vt] = mfma16(ah[ts], bh, kvacc[vt]);
                kvacc[vt] = mfma16(ah[ts], bl, kvacc[vt]);
                kvacc[vt] = mfma16(al[ts], bh, kvacc[vt]);
            }
        }
    }

    float* dst = pkv + ((size_t)(b * PP + p) << 15);
    #pragma unroll
    for (int vt = 0; vt < 4; ++vt)
        #pragma unroll
        for (int r = 0; r < 16; ++r) {
            int feat = nt*32 + rowf(r, q);
            dst[feat * DVV + vt*32 + i] = kvacc[vt][r];
        }
    {
        float s = ksa + __shfl_xor(ksa, 32, 64);
        if (q == 0) pks[(size_t)(b * PP + p) * MM + nt*32 + i] = s;
    }
}

// ---------------------------------------------------------------------------
// reduce: sum P partials -> ksum fp32 + KV as hi/lo f16 B-frags (global)
// ---------------------------------------------------------------------------
__global__ __launch_bounds__(256) void reduce_kernel(const float* __restrict__ pkv,
                                                     const float* __restrict__ pks,
                                                     float* __restrict__ ksum,
                                                     _Float16* __restrict__ kvph,
                                                     _Float16* __restrict__ kvpl) {
    const int b = blockIdx.y;
    int g = blockIdx.x * 256 + threadIdx.x;     // 0..32767
    float s = 0.f;
    for (int p = 0; p < PP; ++p) s += pkv[((size_t)(b * PP + p) << 15) + g];
    int f = g >> 7, v = g & 127;
    int vt = v >> 5, iv = v & 31, fs = f >> 4, qq = (f >> 3) & 1, j = f & 7;
    size_t idx = (size_t)b * 32768 + (size_t)((vt*16 + fs)*64 + qq*32 + iv)*8 + j;
    _Float16 h = (_Float16)s;
    kvph[idx] = h;
    kvpl[idx] = (_Float16)(s - (float)h);
    if (blockIdx.x == 0) {
        float ss = 0.f;
        for (int p = 0; p < PP; ++p) ss += pks[(size_t)(b * PP + p) * MM + g];
        ksum[b * MM + g] = ss;
    }
}

// ---------------------------------------------------------------------------
// out: U_Q -> per-token max -> Qp frags -> Out = Qp@KV (MFMA), norm via MFMA
// grid (64 tokblk, BB), 4 chunks each; omega/KV/Ksum frags register-resident
// (240 VGPR, 2 waves/SIMD, 2 blocks/CU at grid 512). No min-waves bound.
// ---------------------------------------------------------------------------
__global__ __launch_bounds__(256) void out_kernel(const float* __restrict__ Q,
                                                  const float* __restrict__ mask,
                                                  const _Float16* __restrict__ omh,
                                                  const _Float16* __restrict__ oml,
                                                  const float* __restrict__ ksum,
                                                  const _Float16* __restrict__ kvph,
                                                  const _Float16* __restrict__ kvpl,
                                                  float* __restrict__ out) {
    __shared__ __align__(16) _Float16 R1[16 * 520];
    __shared__ __align__(16) _Float16 R2[32 * 520];
    __shared__ float hs[32], msk[32], wmax[4][32], norms[32];
    const int b = blockIdx.y;
    const int tid = threadIdx.x, w = tid >> 6, lane = tid & 63;
    const int i = tid & 31, q = (tid >> 5) & 1;

    f16x8 omf[2][2][8];
    #pragma unroll
    for (int n = 0; n < 2; ++n)
        #pragma unroll
        for (int k = 0; k < 8; ++k) {
            omf[0][n][k] = ((const f16x8*)omh)[((2*w + n)*8 + k)*64 + lane];
            omf[1][n][k] = ((const f16x8*)oml)[((2*w + n)*8 + k)*64 + lane];
        }
    f16x8 bfh[16], bfl[16];   // KV B-frags for this wave's vt=w
    #pragma unroll
    for (int fs = 0; fs < 16; ++fs) {
        bfh[fs] = ((const f16x8*)kvph)[(size_t)b * 4096 + (w*16 + fs)*64 + lane];
        bfl[fs] = ((const f16x8*)kvpl)[(size_t)b * 4096 + (w*16 + fs)*64 + lane];
    }
    f16x8 bnh[4], bnl[4];     // Ksum column frags, fsteps w*4..w*4+3
    #pragma unroll
    for (int u = 0; u < 4; ++u) {
        f16x8 hh, ll;
        #pragma unroll
        for (int j = 0; j < 8; ++j) { hh[j] = (_Float16)0.f; ll[j] = (_Float16)0.f; }
        if (i == 0) {
            #pragma unroll
            for (int j = 0; j < 8; ++j) {
                float s = ksum[b * MM + (4*w + u)*16 + q*8 + j];
                _Float16 h = (_Float16)s;
                hh[j] = h; ll[j] = (_Float16)(s - (float)h);
            }
        }
        bnh[u] = hh; bnl[u] = ll;
    }

    for (int c = 0; c < 4; ++c) {
        int t0 = (blockIdx.x * 4 + c) * CHUNK;
        __syncthreads();
        stage_A(Q + ((size_t)b*NN + t0) * DD, R1, hs, msk,
                mask + (size_t)b*NN + t0, true);
        if (tid < 32) norms[tid] = 1e-8f;
        __syncthreads();

        f32x16 a0, a1;
        #pragma unroll
        for (int r = 0; r < 16; ++r) { a0[r] = 0.f; a1[r] = 0.f; }
        #pragma unroll
        for (int ks = 0; ks < 8; ++ks) {
            f16x8 ah = *(const f16x8*)&R1[FR(ks, lane)];
            f16x8 al = *(const f16x8*)&R1[FR(8 + ks, lane)];
            a0 = mfma16(ah, omf[0][0][ks], a0);
            a0 = mfma16(ah, omf[1][0][ks], a0);
            a0 = mfma16(al, omf[0][0][ks], a0);
            a1 = mfma16(ah, omf[0][1][ks], a1);
            a1 = mfma16(ah, omf[1][1][ks], a1);
            a1 = mfma16(al, omf[0][1][ks], a1);
        }
        float tm[16];
        #pragma unroll
        for (int r = 0; r < 16; ++r) tm[r] = fmaxf(a0[r], a1[r]);
        #pragma unroll
        for (int off = 1; off < 32; off <<= 1)
            #pragma unroll
            for (int r = 0; r < 16; ++r) tm[r] = fmaxf(tm[r], __shfl_xor(tm[r], off, 64));
        if (i == 0)
            #pragma unroll
            for (int r = 0; r < 16; ++r) wmax[w][rowf(r, q)] = tm[r];
        __syncthreads();

        #pragma unroll
        for (int r = 0; r < 16; ++r) {
            int tok = rowf(r, q);
            float tmax = fmaxf(fmaxf(wmax[0][tok], wmax[1][tok]),
                               fmaxf(wmax[2][tok], wmax[3][tok]));
            float hh = hs[tok] + tmax;
            float mm = msk[tok] * INV_SQRT_M;
            #pragma unroll
            for (int n = 0; n < 2; ++n) {
                float qp = (__expf((n ? a1[r] : a0[r]) - hh) + 1e-4f) * mm;
                int feat = (2*w + n)*32 + i;
                int fstep = feat >> 4, fq = (i >> 3) & 1, fj = i & 7;
                _Float16 h = (_Float16)qp;
                R2[FR(fstep, fq*32 + tok) + fj] = h;
                R2[FR(16 + fstep, fq*32 + tok) + fj] = (_Float16)(qp - (float)h);
            }
        }
        __syncthreads();

        f32x16 oa, na;
        #pragma unroll
        for (int r = 0; r < 16; ++r) { oa[r] = 0.f; na[r] = 0.f; }
        #pragma unroll
        for (int fs = 0; fs < 16; ++fs) {
            f16x8 ah = *(const f16x8*)&R2[FR(fs, lane)];
            f16x8 al = *(const f16x8*)&R2[FR(16 + fs, lane)];
            oa = mfma16(ah, bfh[fs], oa);
            oa = mfma16(ah, bfl[fs], oa);
            oa = mfma16(al, bfh[fs], oa);
        }
        #pragma unroll
        for (int u = 0; u < 4; ++u) {
            f16x8 ah = *(const f16x8*)&R2[FR(4*w + u, lane)];
            f16x8 al = *(const f16x8*)&R2[FR(16 + 4*w + u, lane)];
            na = mfma16(ah, bnh[u], na);
            na = mfma16(ah, bnl[u], na);
            na = mfma16(al, bnh[u], na);
        }
        if (i == 0)
            #pragma unroll
            for (int r = 0; r < 16; ++r) atomicAdd(&norms[rowf(r, q)], na[r]);
        __syncthreads();

        float* ob = out + ((size_t)b*NN + t0) * DVV + w*32 + i;
        #pragma unroll
        for (int r = 0; r < 16; ++r) {
            int tok = rowf(r, q);
            ob[(size_t)tok * DVV] = oa[r] / norms[tok];
        }
    }
}

extern "C" void kernel_launch(void* const* d_in, const int* in_sizes, int n_in,
                              void* d_out, int out_size, void* d_ws, size_t ws_size,
                              hipStream_t stream) {
    const float* Q     = (const float*)d_in[0];
    const float* K     = (const float*)d_in[1];
    const float* V     = (const float*)d_in[2];
    const float* mask  = (const float*)d_in[3];
    const float* omega = (const float*)d_in[4];
    float* out = (float*)d_out;

    char* ws = (char*)d_ws;
    _Float16* omh    = (_Float16*)(ws);                       // 64 KB
    _Float16* oml    = (_Float16*)(ws + (64 << 10));          // 64 KB
    unsigned* kmaxord = (unsigned*)(ws + (128 << 10));        // 32 B
    float*    ksum   = (float*)(ws + (132 << 10));            // 8 KB
    float*    pks    = (float*)(ws + (140 << 10));            // 256 KB
    _Float16* kvph   = (_Float16*)(ws + (400 << 10));         // 512 KB
    _Float16* kvpl   = (_Float16*)(ws + (912 << 10));         // 512 KB
    float*    pkv    = (float*)(ws + (2 << 20));              // 32 MB

    pack_kernel<<<16, 256, 0, stream>>>(omega, omh, oml, kmaxord);
    kmax_kernel<<<dim3(32, 2, BB), 256, 0, stream>>>(K, omh, kmaxord);
    kv_kernel<<<dim3(PP, 2, BB), 256, 0, stream>>>(K, V, mask, omh, oml, kmaxord, pkv, pks);
    reduce_kernel<<<dim3(128, BB), 256, 0, stream>>>(pkv, pks, ksum, kvph, kvpl);
    out_kernel<<<dim3(64, BB), 256, 0, stream>>>(Q, mask, omh, oml, ksum, kvph, kvpl, out);
}